// Round 10
// baseline (1547.953 us; speedup 1.0000x reference)
//
#include <hip/hip_runtime.h>
#include <math.h>

#define S_ 2048
#define T_ 64
#define F_ 16
#define D_ 256
#define NS_ 4
#define E_ 128
#define H_ 8
#define SD_ (S_*D_)
#define PS 264   // packed h plane row stride (shorts)

// packed-weight combined buffer (shorts), round-contiguous
#define PK_ATT 0         // 4hp x 8kt x 12288 shorts (Qh,Ql,Kh,Kl,Vh,Vl x 2048)
#define PK_WO  393216    // 8 kt-tiles x 16384 (hi 8192 | lo 8192)
#define PK_WI  524288
#define PK_WT  655360
#define PK_WM  786432    // 16 kt-tiles
#define PKBASE 11674112  // float offset in ws where pkc starts (2MB)
// secondary packed buffer (tail GEMM weights), lives in dead ws region
#define PK2BASE 5242880  // float offset; 6 x 131072 shorts = 1.5MB
#define PKH1 0
#define PKH2 131072
#define PKA  262144
#define PKB  393216
#define PKG  524288
#define PKM1 655360

typedef __attribute__((ext_vector_type(8))) short bf16x8;
typedef __attribute__((ext_vector_type(4))) float f32x4;

// ---------------- helpers ----------------
__device__ __forceinline__ float warp_sum64(float v){
  #pragma unroll
  for (int o=32;o>=1;o>>=1) v += __shfl_xor(v,o);
  return v;
}
__device__ __forceinline__ float warp_max64(float v){
  #pragma unroll
  for (int o=32;o>=1;o>>=1) v = fmaxf(v,__shfl_xor(v,o));
  return v;
}
__device__ __forceinline__ float softplus_f(float v){
  return fmaxf(v,0.f) + log1pf(__expf(-fabsf(v)));
}
__device__ __forceinline__ float tanh_f(float v){
  float t = __expf(-2.f*fabsf(v));
  float r = (1.f-t)/(1.f+t);
  return copysignf(r, v);
}
// split fp32 into bf16 hi + bf16 lo (RNE)
__device__ __forceinline__ void splitf(float f, short& h, short& l){
  unsigned u = __float_as_uint(f);
  unsigned hb = (u + 0x7FFFu + ((u>>16)&1u)) >> 16;
  float fl = f - __uint_as_float(hb<<16);
  unsigned v = __float_as_uint(fl);
  unsigned lb = (v + 0x7FFFu + ((v>>16)&1u)) >> 16;
  h = (short)hb; l = (short)lb;
}
__device__ __forceinline__ f32x4 mfma3(bf16x8 ah, bf16x8 al, bf16x8 bh, bf16x8 bl, f32x4 c){
  c = __builtin_amdgcn_mfma_f32_16x16x32_bf16(al, bh, c, 0,0,0);
  c = __builtin_amdgcn_mfma_f32_16x16x32_bf16(ah, bl, c, 0,0,0);
  c = __builtin_amdgcn_mfma_f32_16x16x32_bf16(ah, bh, c, 0,0,0);
  return c;
}
__device__ __forceinline__ void afrag_f32(const float* base, int stride, int rbase, int ks, int lane, bf16x8& hi, bf16x8& lo){
  const float* p = base + (rbase + (lane&15))*stride + ks + ((lane>>4)<<3);
  #pragma unroll
  for (int jj=0;jj<8;++jj){ short h,l; splitf(p[jj],h,l); hi[jj]=h; lo[jj]=l; }
}
__device__ __forceinline__ bf16x8 afrag_pk(const short* plane, int rbase, int ks, int lane){
  return *(const bf16x8*)(plane + (rbase + (lane&15))*PS + ks + ((lane>>4)<<3));
}
__device__ __forceinline__ void bfrag_pk(const unsigned* pk, int tile, int lane, bf16x8& hi, bf16x8& lo){
  const unsigned* p = pk + (((tile<<6) + lane)<<3);
  #pragma unroll
  for (int jj=0;jj<8;++jj){ unsigned u=p[jj]; hi[jj]=(short)(u & 0xffffu); lo[jj]=(short)(u>>16); }
}
__device__ __forceinline__ void store_h(short* Hh, short* Hl, int r, int c, float f){
  short h,l; splitf(f,h,l);
  Hh[r*PS+c]=h; Hl[r*PS+c]=l;
}
__device__ __forceinline__ float load_h(const short* Hh, const short* Hl, int r, int c){
  int idx=r*PS+c;
  return __uint_as_float(((unsigned)(unsigned short)Hh[idx])<<16)
       + __uint_as_float(((unsigned)(unsigned short)Hl[idx])<<16);
}

// ---------------- weight packing (all 13 targets in one launch) ----------------
__global__ void pack_all(const float* __restrict__ Wq, const float* __restrict__ Wk,
                         const float* __restrict__ Wv, const float* __restrict__ Wo,
                         const float* __restrict__ Wint, const float* __restrict__ Wt,
                         const float* __restrict__ Wmix,
                         const float* __restrict__ Wh1, const float* __restrict__ Wh2,
                         const float* __restrict__ Wa, const float* __restrict__ Wb,
                         const float* __restrict__ Wg, const float* __restrict__ Wm1,
                         short* __restrict__ pkc, short* __restrict__ pk2){
  int y = blockIdx.y;
  int i = blockIdx.x*256 + threadIdx.x;   // 65536
  if (y < 3){
    const float* W = (y==0)?Wq:((y==1)?Wk:Wv);
    int jj=i&7, n=(i>>3)&15, q=(i>>7)&3, ntg=(i>>9)&15, kt=i>>13;
    float f = W[(kt*32 + q*8 + jj)*256 + (ntg*16+n)];
    short h,l; splitf(f,h,l);
    int hp = ntg>>2, ntl = ntg&3;
    int base = ((hp*8+kt)*6 + y*2)*2048;
    int local = ntl*512 + (q*16+n)*8 + jj;
    short* dst = pkc + PK_ATT;
    dst[base+local] = h;
    dst[base+2048+local] = l;
  } else {
    const float* W; short* dst; int ib = i;
    if (y==3){W=Wo;   dst=pkc+PK_WO;}
    else if (y==4){W=Wint; dst=pkc+PK_WI;}
    else if (y==5){W=Wt;   dst=pkc+PK_WT;}
    else if (y==6){W=Wmix; dst=pkc+PK_WM;}
    else if (y==7){W=Wmix; dst=pkc+PK_WM; ib = i + 65536;}
    else if (y==8){W=Wh1;  dst=pk2+PKH1;}
    else if (y==9){W=Wh2;  dst=pk2+PKH2;}
    else if (y==10){W=Wa;  dst=pk2+PKA;}
    else if (y==11){W=Wb;  dst=pk2+PKB;}
    else if (y==12){W=Wg;  dst=pk2+PKG;}
    else          {W=Wm1;  dst=pk2+PKM1;}
    int jj=ib&7, n=(ib>>3)&15, q=(ib>>7)&3, ntg=(ib>>9)&15, kt=ib>>13;
    float f = W[(kt*32 + q*8 + jj)*256 + (ntg*16+n)];
    short h,l; splitf(f,h,l);
    int dl = kt*16384 + ntg*512 + (q*16+n)*8 + jj;
    dst[dl] = h; dst[dl+8192] = l;
  }
}

// ---------------- positional encoding ----------------
__global__ void pe_kernel(float* __restrict__ pe){
  int i = blockIdx.x*256 + threadIdx.x;       // grid 64 -> 16384
  int t = i >> 8, d = i & 255;
  int ii = d >> 1;
  float w = __expf(-(float)ii * (logf(10000.f)/128.f));
  float ang = (float)t * w;
  pe[i] = (d & 1) ? cosf(ang) : sinf(ang);
}

// ---------------- stage A (R6 structure: best measured) ----------------
// LDS: planes 2x33792 + smem 85504 = 153088 B -> 1 block/CU, 8 waves (2/SIMD)
__launch_bounds__(512,1)
__global__ void stageA_kernel(
    const float* __restrict__ x, const float* __restrict__ pe,
    const float* __restrict__ Wemb, const float* __restrict__ bemb,
    const float* __restrict__ bq, const float* __restrict__ bk, const float* __restrict__ bv,
    const float* __restrict__ bo,
    const float* __restrict__ ln1g, const float* __restrict__ ln1b,
    const float* __restrict__ bint,
    const float* __restrict__ bmix,
    const float* __restrict__ ln2g, const float* __restrict__ ln2b,
    const float* __restrict__ bt,
    const float* __restrict__ vt,
    const short* __restrict__ pkc,
    float* __restrict__ xs)
{
  __shared__ __attribute__((aligned(16))) short hbh[64*PS];   // 33792 B
  __shared__ __attribute__((aligned(16))) short hbl[64*PS];   // 33792 B
  __shared__ __attribute__((aligned(16))) char smem[85504];

  short*    wst   = (short*)smem;                      // QKV staging 24KB
  unsigned* k2f2  = (unsigned*)smem;                   // overlay: 2 heads x 2048 u32
  unsigned* v2f2  = (unsigned*)(smem + 16384);         // 16KB
  float*    qb2   = (float*)(smem + 32768);            // [64][68] q / o_h
  float*    scb2  = (float*)(smem + 50176);            // 2 x [64][68] probs
  float*    poolb = (float*)smem;                      // overlay post-attention

  const int j  = threadIdx.x;
  const int s  = blockIdx.x;
  const int w  = j >> 6;            // wave 0..7
  const int lane = j & 63;
  const int m_ = lane & 15, qd = lane >> 4;
  const int rg2 = w >> 1, par = w & 1;
  const int rbase = rg2*16;
  const int rv = w*8;
  const int c0 = lane;

  // ---- stage x[s] ----
  {
    float* xb = (float*)smem;
    const float* xp = x + (long)s*T_*F_;
    for (int i=j; i<T_*F_; i+=512) xb[i] = xp[i];
  }
  __syncthreads();

  // ---- embedding + PE -> packed planes ----
  {
    const float* xb = (const float*)smem;
    float acc[8][4];
    #pragma unroll
    for (int r=0;r<8;++r){acc[r][0]=0;acc[r][1]=0;acc[r][2]=0;acc[r][3]=0;}
    #pragma unroll
    for (int k=0;k<F_;++k){
      float w0=Wemb[k*D_+c0], w1=Wemb[k*D_+c0+64], w2=Wemb[k*D_+c0+128], w3=Wemb[k*D_+c0+192];
      #pragma unroll
      for (int r=0;r<8;++r){
        float hv = xb[(rv+r)*F_+k];
        acc[r][0]+=hv*w0; acc[r][1]+=hv*w1; acc[r][2]+=hv*w2; acc[r][3]+=hv*w3;
      }
    }
    float b0=bemb[c0],b1=bemb[c0+64],b2=bemb[c0+128],b3=bemb[c0+192];
    __syncthreads();
    #pragma unroll
    for (int r=0;r<8;++r){
      int t = rv+r;
      store_h(hbh,hbl,t,c0,     acc[r][0]+b0+pe[t*D_+c0]);
      store_h(hbh,hbl,t,c0+64,  acc[r][1]+b1+pe[t*D_+c0+64]);
      store_h(hbh,hbl,t,c0+128, acc[r][2]+b2+pe[t*D_+c0+128]);
      store_h(hbh,hbl,t,c0+192, acc[r][3]+b3+pe[t*D_+c0+192]);
    }
  }
  __syncthreads();

  // ---- hoist QKV A-fragments ----
  bf16x8 AH[8], AL[8];
  #pragma unroll
  for (int kt=0;kt<8;++kt){
    AH[kt] = afrag_pk(hbh, rbase, kt*32, lane);
    AL[kt] = afrag_pk(hbl, rbase, kt*32, lane);
  }

  const float rs = 0.17677669529663687f;  // 1/sqrt(32)
  f32x4 co[8];
  #pragma unroll
  for (int t=0;t<8;++t) co[t] = (f32x4){0.f,0.f,0.f,0.f};

  // ---- attention: head pairs, head = parity ----
  for (int hp=0; hp<4; ++hp){
    f32x4 qa[2],ka[2],va[2];
    #pragma unroll
    for (int t=0;t<2;++t){
      qa[t]=(f32x4){0.f,0.f,0.f,0.f};
      ka[t]=(f32x4){0.f,0.f,0.f,0.f};
      va[t]=(f32x4){0.f,0.f,0.f,0.f};
    }
    bf16x8 pre[3];
    {
      const short* b0 = pkc + PK_ATT + (hp*8)*12288;
      #pragma unroll
      for (int r=0;r<3;++r) pre[r] = *(const bf16x8*)(b0 + (j+r*512)*8);
    }
    for (int kt=0; kt<8; ++kt){
      __syncthreads();
      #pragma unroll
      for (int r=0;r<3;++r) *(bf16x8*)(wst + (j+r*512)*8) = pre[r];
      __syncthreads();
      if (kt<7){
        const short* nb = pkc + PK_ATT + (hp*8+kt+1)*12288;
        #pragma unroll
        for (int r=0;r<3;++r) pre[r] = *(const bf16x8*)(nb + (j+r*512)*8);
      }
      bf16x8 ah = AH[kt], al = AL[kt];
      #pragma unroll
      for (int t=0;t<2;++t){
        int ntl = par*2+t;
        bf16x8 bh,bl;
        bh = *(bf16x8*)(wst +         ntl*512 + lane*8);
        bl = *(bf16x8*)(wst + 2048  + ntl*512 + lane*8);
        qa[t]=mfma3(ah,al,bh,bl,qa[t]);
        bh = *(bf16x8*)(wst + 4096  + ntl*512 + lane*8);
        bl = *(bf16x8*)(wst + 6144  + ntl*512 + lane*8);
        ka[t]=mfma3(ah,al,bh,bl,ka[t]);
        bh = *(bf16x8*)(wst + 8192  + ntl*512 + lane*8);
        bl = *(bf16x8*)(wst + 10240 + ntl*512 + lane*8);
        va[t]=mfma3(ah,al,bh,bl,va[t]);
      }
    }
    __syncthreads();   // QKV reads done; epilogue overwrites staging region
    // epilogue: q->qb2 (scaled), k/v -> packed B-frag LDS
    #pragma unroll
    for (int t=0;t<2;++t){
      int ntg = par*2+t;
      #pragma unroll
      for (int r=0;r<4;++r){
        int trow = rbase + qd*4 + r;
        int pcp = ntg*16 + m_;
        int head = pcp >> 5;
        int cp = pcp & 31;
        int col = hp*64 + pcp;
        qb2[trow*68 + pcp] = (qa[t][r] + bq[col]) * rs;
        short hS,lS;
        float kv2 = ka[t][r] + bk[col];
        splitf(kv2,hS,lS);
        k2f2[head*2048 + (((trow>>4)*4 + (cp>>3))*16 + (trow&15))*8 + (cp&7)]
            = (unsigned)(unsigned short)hS | ((unsigned)(unsigned short)lS<<16);
        float vv2 = va[t][r] + bv[col];
        splitf(vv2,hS,lS);
        v2f2[head*2048 + ((((trow>>5)*2 + (cp>>4))*4 + ((trow>>3)&3))*16 + (cp&15))*8 + (trow&7)]
            = (unsigned)(unsigned short)hS | ((unsigned)(unsigned short)lS<<16);
      }
    }
    __syncthreads();   // k2f2/v2f2/qb2 visible
    // ---- scores + softmax (head = par) ----
    float* scb = scb2 + par*4352;
    {
      bf16x8 ah,al;
      afrag_f32(qb2, 68, rbase, par*32, lane, ah, al);
      f32x4 sc4[4];
      #pragma unroll
      for (int nt=0;nt<4;++nt){
        bf16x8 bh,bl; bfrag_pk(k2f2 + par*2048, nt, lane, bh, bl);
        sc4[nt] = mfma3(ah,al,bh,bl,(f32x4){0.f,0.f,0.f,0.f});
      }
      #pragma unroll
      for (int r=0;r<4;++r){
        float mx = fmaxf(fmaxf(sc4[0][r],sc4[1][r]),fmaxf(sc4[2][r],sc4[3][r]));
        #pragma unroll
        for (int o=8;o>=1;o>>=1) mx = fmaxf(mx, __shfl_xor(mx,o));
        float es = 0.f;
        #pragma unroll
        for (int nt=0;nt<4;++nt){ float e=__expf(sc4[nt][r]-mx); sc4[nt][r]=e; es+=e; }
        #pragma unroll
        for (int o=8;o>=1;o>>=1) es += __shfl_xor(es,o);
        float inv = 1.f/es;
        int trow = rbase + qd*4 + r;
        #pragma unroll
        for (int nt=0;nt<4;++nt) scb[trow*68 + nt*16 + m_] = sc4[nt][r]*inv;
      }
    }
    // ---- o = P @ V (head = par) ----
    {
      f32x4 oa[2];
      oa[0]=(f32x4){0.f,0.f,0.f,0.f}; oa[1]=(f32x4){0.f,0.f,0.f,0.f};
      #pragma unroll
      for (int kt=0;kt<2;++kt){
        bf16x8 ah2,al2; afrag_f32(scb, 68, rbase, kt*32, lane, ah2, al2);
        #pragma unroll
        for (int nt=0;nt<2;++nt){
          bf16x8 bh,bl; bfrag_pk(v2f2 + par*2048, kt*2+nt, lane, bh, bl);
          oa[nt]=mfma3(ah2,al2,bh,bl,oa[nt]);
        }
      }
      #pragma unroll
      for (int nt=0;nt<2;++nt){
        #pragma unroll
        for (int r=0;r<4;++r)
          qb2[(rbase+qd*4+r)*68 + par*32 + nt*16 + m_] = oa[nt][r];
      }
    }
    __syncthreads();   // PV writes to qb2 visible (Wo reads both heads' cols)
    // ---- Wo accumulate: B direct from global ----
    for (int ks=0; ks<2; ++ks){
      bf16x8 ah,al; afrag_f32(qb2, 68, rbase, ks*32, lane, ah, al);
      const short* wob = pkc + PK_WO + (hp*2+ks)*16384 + lane*8;
      #pragma unroll
      for (int t=0;t<8;++t){
        int ntg = 2*t+par;
        bf16x8 bh = *(const bf16x8*)(wob + ntg*512);
        bf16x8 bl = *(const bf16x8*)(wob + 8192 + ntg*512);
        co[t]=mfma3(ah,al,bh,bl,co[t]);
      }
    }
  }

  // ---- residual + bo -> planes ----
  #pragma unroll
  for (int t=0;t<8;++t){
    int cc = (2*t+par)*16+m_;
    float bov = bo[cc];
    #pragma unroll
    for (int r=0;r<4;++r){
      int row = rbase+qd*4+r;
      store_h(hbh,hbl,row,cc, load_h(hbh,hbl,row,cc) + co[t][r] + bov);
    }
  }
  __syncthreads();

  // ---- LN1 ----
  {
    float g0=ln1g[c0],g1=ln1g[c0+64],g2=ln1g[c0+128],g3=ln1g[c0+192];
    float bb0=ln1b[c0],bb1=ln1b[c0+64],bb2=ln1b[c0+128],bb3=ln1b[c0+192];
    for (int rr=0;rr<8;++rr){
      int t=rv+rr;
      float v0=load_h(hbh,hbl,t,c0),    v1=load_h(hbh,hbl,t,c0+64);
      float v2=load_h(hbh,hbl,t,c0+128),v3=load_h(hbh,hbl,t,c0+192);
      float sm=warp_sum64(v0+v1+v2+v3);
      float sq=warp_sum64(v0*v0+v1*v1+v2*v2+v3*v3);
      float mean=sm*(1.f/256.f);
      float inv=rsqrtf(fmaxf(sq*(1.f/256.f)-mean*mean,0.f)+1e-5f);
      store_h(hbh,hbl,t,c0,    (v0-mean)*inv*g0+bb0);
      store_h(hbh,hbl,t,c0+64, (v1-mean)*inv*g1+bb1);
      store_h(hbh,hbl,t,c0+128,(v2-mean)*inv*g2+bb2);
      store_h(hbh,hbl,t,c0+192,(v3-mean)*inv*g3+bb3);
    }
  }
  __syncthreads();

  // ---- post GEMMs: M=64/wave, nt={2w,2w+1}, B direct from global w/ prefetch ----
  auto loadB=[&](bf16x8* d, const short* base, int kt){
    const short* p = base + kt*16384 + lane*8;
    d[0]=*(const bf16x8*)(p + (2*w)*512);
    d[1]=*(const bf16x8*)(p + 8192 + (2*w)*512);
    d[2]=*(const bf16x8*)(p + (2*w+1)*512);
    d[3]=*(const bf16x8*)(p + 8192 + (2*w+1)*512);
  };
  const short* BM = pkc + PK_WM;
  const short* BI = pkc + PK_WI;
  const short* BT = pkc + PK_WT;

  f32x4 az[4][2], ai[4][2];
  #pragma unroll
  for (int rt=0;rt<4;++rt){
    az[rt][0]=(f32x4){0.f,0.f,0.f,0.f}; az[rt][1]=(f32x4){0.f,0.f,0.f,0.f};
    ai[rt][0]=(f32x4){0.f,0.f,0.f,0.f}; ai[rt][1]=(f32x4){0.f,0.f,0.f,0.f};
  }
  bf16x8 cb[4], nb[4];
  loadB(cb, BM, 0);
  // Wmix part1 (A = h)
  for (int kt=0; kt<8; ++kt){
    if (kt<7) loadB(nb, BM, kt+1); else loadB(nb, BI, 0);
    #pragma unroll
    for (int rt=0;rt<4;++rt){
      bf16x8 ah = afrag_pk(hbh, rt*16, kt*32, lane);
      bf16x8 al = afrag_pk(hbl, rt*16, kt*32, lane);
      az[rt][0]=mfma3(ah,al,cb[0],cb[1],az[rt][0]);
      az[rt][1]=mfma3(ah,al,cb[2],cb[3],az[rt][1]);
    }
    #pragma unroll
    for (int r=0;r<4;++r) cb[r]=nb[r];
  }
  // Wint (A = h)
  for (int kt=0; kt<8; ++kt){
    if (kt<7) loadB(nb, BI, kt+1); else loadB(nb, BM, 8);
    #pragma unroll
    for (int rt=0;rt<4;++rt){
      bf16x8 ah = afrag_pk(hbh, rt*16, kt*32, lane);
      bf16x8 al = afrag_pk(hbl, rt*16, kt*32, lane);
      ai[rt][0]=mfma3(ah,al,cb[0],cb[1],ai[rt][0]);
      ai[rt][1]=mfma3(ah,al,cb[2],cb[3],ai[rt][1]);
    }
    #pragma unroll
    for (int r=0;r<4;++r) cb[r]=nb[r];
  }
  __syncthreads();
  // intensity -> planes
  #pragma unroll
  for (int rt=0;rt<4;++rt){
    #pragma unroll
    for (int t=0;t<2;++t){
      int col=(2*w+t)*16+m_;
      float bb=bint[col];
      #pragma unroll
      for (int r=0;r<4;++r)
        store_h(hbh,hbl, rt*16+qd*4+r, col, softplus_f(ai[rt][t][r]+bb));
    }
  }
  __syncthreads();
  // Wmix part2 (A = intensity, B tiles 8..15)
  for (int kt=0; kt<8; ++kt){
    if (kt<7) loadB(nb, BM, kt+9); else loadB(nb, BT, 0);
    #pragma unroll
    for (int rt=0;rt<4;++rt){
      bf16x8 ah = afrag_pk(hbh, rt*16, kt*32, lane);
      bf16x8 al = afrag_pk(hbl, rt*16, kt*32, lane);
      az[rt][0]=mfma3(ah,al,cb[0],cb[1],az[rt][0]);
      az[rt][1]=mfma3(ah,al,cb[2],cb[3],az[rt][1]);
    }
    #pragma unroll
    for (int r=0;r<4;++r) cb[r]=nb[r];
  }
  __syncthreads();
  // z = relu -> planes
  #pragma unroll
  for (int rt=0;rt<4;++rt){
    #pragma unroll
    for (int t=0;t<2;++t){
      int col=(2*w+t)*16+m_;
      float bb=bmix[col];
      #pragma unroll
      for (int r=0;r<4;++r)
        store_h(hbh,hbl, rt*16+qd*4+r, col, fmaxf(az[rt][t][r]+bb,0.f));
    }
  }
  __syncthreads();
  // ---- LN2 ----
  {
    float g0=ln2g[c0],g1=ln2g[c0+64],g2=ln2g[c0+128],g3=ln2g[c0+192];
    float bb0=ln2b[c0],bb1=ln2b[c0+64],bb2=ln2b[c0+128],bb3=ln2b[c0+192];
    for (int rr=0;rr<8;++rr){
      int t=rv+rr;
      float v0=load_h(hbh,hbl,t,c0),    v1=load_h(hbh,hbl,t,c0+64);
      float v2=load_h(hbh,hbl,t,c0+128),v3=load_h(hbh,hbl,t,c0+192);
      float sm=warp_sum64(v0+v1+v2+v3);
      float sq=warp_sum64(v0*v0+v1*v1+v2*v2+v3*v3);
      float mean=sm*(1.f/256.f);
      float inv=rsqrtf(fmaxf(sq*(1.f/256.f)-mean*mean,0.f)+1e-5f);
      store_h(hbh,hbl,t,c0,    (v0-mean)*inv*g0+bb0);
      store_h(hbh,hbl,t,c0+64, (v1-mean)*inv*g1+bb1);
      store_h(hbh,hbl,t,c0+128,(v2-mean)*inv*g2+bb2);
      store_h(hbh,hbl,t,c0+192,(v3-mean)*inv*g3+bb3);
    }
  }
  __syncthreads();
  // ---- Wt: u = tanh(h@Wt+bt), pooled ----
  {
    f32x4 at4[4][2];
    #pragma unroll
    for (int rt=0;rt<4;++rt){
      at4[rt][0]=(f32x4){0.f,0.f,0.f,0.f}; at4[rt][1]=(f32x4){0.f,0.f,0.f,0.f};
    }
    for (int kt=0; kt<8; ++kt){
      if (kt<7) loadB(nb, BT, kt+1);
      #pragma unroll
      for (int rt=0;rt<4;++rt){
        bf16x8 ah = afrag_pk(hbh, rt*16, kt*32, lane);
        bf16x8 al = afrag_pk(hbl, rt*16, kt*32, lane);
        at4[rt][0]=mfma3(ah,al,cb[0],cb[1],at4[rt][0]);
        at4[rt][1]=mfma3(ah,al,cb[2],cb[3],at4[rt][1]);
      }
      #pragma unroll
      for (int r=0;r<4;++r) cb[r]=nb[r];
    }
    #pragma unroll
    for (int rt=0;rt<4;++rt){
      #pragma unroll
      for (int r=0;r<4;++r){
        int row = rt*16+qd*4+r;
        float p = 0.f;
        #pragma unroll
        for (int t=0;t<2;++t){
          int col=(2*w+t)*16+m_;
          p += tanh_f(at4[rt][t][r]+bt[col])*vt[col];
        }
        p += __shfl_xor(p,1); p += __shfl_xor(p,2);
        p += __shfl_xor(p,4); p += __shfl_xor(p,8);
        if (m_==0) poolb[w*64+row] = p;
      }
    }
  }
  __syncthreads();
  if (j < 64){
    float v = 0.f;
    #pragma unroll
    for (int ww=0;ww<8;++ww) v += poolb[ww*64+j];
    float m = warp_max64(v);
    float e = __expf(v-m);
    float ssum = warp_sum64(e);
    poolb[512+j] = e/ssum;
  }
  __syncthreads();
  if (j < 256){
    float acc=0.f;
    #pragma unroll 8
    for (int t=0;t<T_;++t) acc += poolb[512+t]*load_h(hbh,hbl,t,j);
    xs[(long)s*D_+j] = acc;
  }
}

// ---------------- hypergraph degrees ----------------
__global__ void hg_deg(const float* __restrict__ Hinc, float* __restrict__ Dv, float* __restrict__ De){
  const int n = blockIdx.y, s0 = blockIdx.x*64;   // grid (32, NS)
  const float* Hp = Hinc + (long)n*S_*E_;
  const int j = threadIdx.x;
  {
    int r = j>>2, q = j&3;
    const float* rp = Hp + (long)(s0+r)*E_ + q*32;
    float sm=0;
    #pragma unroll
    for (int e=0;e<32;++e) sm += rp[e];
    sm += __shfl_xor(sm,1); sm += __shfl_xor(sm,2);
    if (q==0) Dv[n*S_+s0+r]=sm+1e-6f;
  }
  if (j < E_){
    float cs=0;
    for (int ss=0;ss<64;++ss) cs += Hp[(long)(s0+ss)*E_+j];
    atomicAdd(&De[n*E_+j], cs);
  }
}

// ---------------- CSR builds (deterministic, ascending index order) ----------------
__global__ void build_ecsr(const float* __restrict__ snap, const float* __restrict__ Dv,
                           int* __restrict__ ei, float* __restrict__ ev, int* __restrict__ ecnt){
  __shared__ int cnts[257];
  const int e = blockIdx.x, n = blockIdx.y, t = threadIdx.x;
  const float* col = snap + (long)n*S_*E_ + e;
  int loc[8]; int c=0;
  #pragma unroll
  for (int r=0;r<8;++r){
    int s = t*8+r;
    if (col[(long)s*E_] != 0.f) loc[c++]=s;
  }
  cnts[t+1]=c;
  __syncthreads();
  if (t==0){ cnts[0]=0; for (int i=1;i<=256;++i) cnts[i]+=cnts[i-1]; }
  __syncthreads();
  int base = cnts[t];
  long eb = ((long)n*E_+e)*256;
  for (int k=0;k<c;++k){
    int pos = base+k;
    if (pos<256){ ei[eb+pos]=loc[k]; ev[eb+pos]=rsqrtf(Dv[n*S_+loc[k]]); }
  }
  if (t==255) ecnt[n*E_+e] = min(cnts[256],256);
}
__global__ void build_scsr(const float* __restrict__ snap, const float* __restrict__ Dv,
                           const float* __restrict__ De,
                           int* __restrict__ si, float* __restrict__ sv, int* __restrict__ scnt){
  const int s = blockIdx.x*256+threadIdx.x, n = blockIdx.y;
  const float* row = snap + ((long)n*S_+s)*E_;
  float vs = rsqrtf(Dv[n*S_+s]);
  long sb = ((long)n*S_+s)*32;
  int c=0;
  for (int e=0;e<E_;++e){
    if (row[e]!=0.f && c<32){
      si[sb+c]=e;
      sv[sb+c]=vs/(De[n*E_+e]+1e-6f);
      ++c;
    }
  }
  scnt[n*S_+s]=c;
}

// ---------------- sparse hypergraph apply (throughput-shaped) ----------------
__launch_bounds__(256,4)
__global__ void hg_p1(const int* __restrict__ ei, const float* __restrict__ ev,
                      const int* __restrict__ ecnt,
                      const float* __restrict__ M, long mz, float* __restrict__ P){
  __shared__ int sidx[256];
  __shared__ float sval[256];
  const int e = blockIdx.x, n = blockIdx.y, d = threadIdx.x;   // grid (E_, NS_)
  long eb = ((long)n*E_+e)*256;
  const int c = ecnt[n*E_+e];
  if (d < c){ sidx[d]=ei[eb+d]; sval[d]=ev[eb+d]; }
  __syncthreads();
  const float* Mp = M + (long)n*mz;
  float a0=0.f,a1=0.f,a2=0.f,a3=0.f;
  int i=0;
  for (; i+4<=c; i+=4){
    float m0 = Mp[(long)sidx[i+0]*D_+d];
    float m1 = Mp[(long)sidx[i+1]*D_+d];
    float m2 = Mp[(long)sidx[i+2]*D_+d];
    float m3 = Mp[(long)sidx[i+3]*D_+d];
    a0 += sval[i+0]*m0; a1 += sval[i+1]*m1;
    a2 += sval[i+2]*m2; a3 += sval[i+3]*m3;
  }
  for (; i<c; ++i) a0 += sval[i]*Mp[(long)sidx[i]*D_+d];
  P[((long)n*E_+e)*D_+d] = (a0+a1)+(a2+a3);
}
__launch_bounds__(256,4)
__global__ void hg_p2(const int* __restrict__ si, const float* __restrict__ sv,
                      const int* __restrict__ scnt, const float* __restrict__ P,
                      const float* __restrict__ X1, long x1z, float c1,
                      const float* __restrict__ X2, long x2z, float c2,
                      float c3, const float* __restrict__ filt, int usefilt,
                      float* __restrict__ out){
  __shared__ int sidx[8][32];
  __shared__ float sval[8][32];
  __shared__ int scc[8];
  const int s0 = blockIdx.x*8, n = blockIdx.y, d = threadIdx.x;  // grid (S_/8, NS_)
  {
    int k = d>>5, i = d&31;
    long sb = ((long)n*S_+s0+k)*32;
    sidx[k][i] = si[sb+i];
    sval[k][i] = sv[sb+i];
    if (i==0) scc[k] = scnt[n*S_+s0+k];
  }
  __syncthreads();
  const float* Pn = P + (long)n*E_*D_;
  #pragma unroll
  for (int k=0;k<8;++k){
    int s = s0+k;
    int c = scc[k];
    float acc=0.f;
    for (int i=0;i<c;++i) acc += sval[k][i]*Pn[(long)sidx[k][i]*D_+d];
    long li=(long)s*D_+d;
    float v=c3*acc;
    if (X1) v+=c1*X1[x1z*n+li];
    if (X2) v+=c2*X2[x2z*n+li];
    out[((long)n*S_+s)*D_+d]=(usefilt?filt[s]:1.f)*v;
  }
}

// ---------------- MFMA tail GEMM: C[M x 256] = act(A[M x 256] @ Wpk + bias) ----------------
// A fp32 row-major (split on the fly); Wpk packed hi/lo fragment-ordered (pack_post format).
// grid (M/64), block 256 = 4 waves x 16 rows.
__launch_bounds__(256,4)
__global__ void gemm_pk(const float* __restrict__ A, const short* __restrict__ Bpk,
                        float* __restrict__ C, const float* __restrict__ bias, int act)
{
  const int j = threadIdx.x;
  const int w = j>>6, lane = j&63;
  const int m_ = lane&15, qd = lane>>4;
  const long r0 = (long)blockIdx.x*64 + w*16;
  f32x4 acc[16];
  #pragma unroll
  for (int nt=0;nt<16;++nt) acc[nt]=(f32x4){0.f,0.f,0.f,0.f};
  #pragma unroll
  for (int kt=0; kt<8; ++kt){
    bf16x8 ah, al;
    {
      const float* p = A + (r0 + m_)*D_ + kt*32 + (qd<<3);
      #pragma unroll
      for (int jj=0;jj<8;++jj){ short h,l; splitf(p[jj],h,l); ah[jj]=h; al[jj]=l; }
    }
    const short* bp = Bpk + kt*16384 + lane*8;
    #pragma unroll
    for (int nt=0;nt<16;++nt){
      bf16x8 bh = *(const bf16x8*)(bp + nt*512);
      bf16x8 bl = *(const bf16x8*)(bp + 8192 + nt*512);
      acc[nt]=mfma3(ah,al,bh,bl,acc[nt]);
    }
  }
  #pragma unroll
  for (int nt=0;nt<16;++nt){
    int col = nt*16+m_;
    float bb = bias ? bias[col] : 0.f;
    #pragma unroll
    for (int r=0;r<4;++r){
      float v = acc[nt][r]+bb;
      if (act==1) v=fmaxf(v,0.f);
      else if (act==2) v=(v>0.f)?v:0.1f*v;
      C[(r0+qd*4+r)*D_ + col] = v;
    }
  }
}

// ---------------- MFMA NT GEMM: C[2048x2048] = scale * A @ B^T (both fp32 [2048x256]) ----------------
__launch_bounds__(256,4)
__global__ void gemm_nt_pk(const float* __restrict__ A, const float* __restrict__ B,
                           float* __restrict__ C, float scale)
{
  const int j = threadIdx.x;
  const int w = j>>6, lane = j&63;
  const int m_ = lane&15, qd = lane>>4;
  const long r0 = (long)blockIdx.x*64 + w*16;
  const long c0 = (long)blockIdx.y*64;
  f32x4 acc[4];
  #pragma unroll
  for (int nt=0;nt<4;++nt) acc[nt]=(f32x4){0.f,0.f,0.f,0.f};
  #pragma unroll
  for (int kt=0; kt<8; ++kt){
    bf16x8 ah, al;
    {
      const float* p = A + (r0 + m_)*D_ + kt*32 + (qd<<3);
      #pragma unroll
      for (int jj=0;jj<8;++jj){ short h,l; splitf(p[jj],h,l); ah[jj]=h; al[jj]=l; }
    }
    #pragma unroll
    for (int nt=0;nt<4;++nt){
      bf16x8 bh, bl;
      const float* p = B + (c0 + nt*16 + m_)*D_ + kt*32 + (qd<<3);
      #pragma unroll
      for (int jj=0;jj<8;++jj){ short h,l; splitf(p[jj],h,l); bh[jj]=h; bl[jj]=l; }
      acc[nt]=mfma3(ah,al,bh,bl,acc[nt]);
    }
  }
  #pragma unroll
  for (int nt=0;nt<4;++nt){
    #pragma unroll
    for (int r=0;r<4;++r)
      C[(r0+qd*4+r)*S_ + c0 + nt*16 + m_] = acc[nt][r]*scale;
  }
}

// ---------------- top-k (register-resident) + sparse softmax-gather ----------------
__launch_bounds__(256,4)
__global__ void topk_gather(const float* __restrict__ sim, const float* __restrict__ xs,
                            const int* __restrict__ Kp, float* __restrict__ dynpre)
{
  __shared__ float wred[4]; __shared__ int ired[4];
  __shared__ float selw[256]; __shared__ int seli[256];
  __shared__ int cnt; __shared__ float sh_kth, sh_max, sh_den; __shared__ int sh_bi;
  const int s = blockIdx.x, j = threadIdx.x;
  const float* rp = sim + (long)s*S_;
  float vo[8], v[8];
  *(float4*)&vo[0] = *(const float4*)&rp[j*8];
  *(float4*)&vo[4] = *(const float4*)&rp[j*8+4];
  #pragma unroll
  for (int r=0;r<8;++r) v[r]=vo[r];
  if (j==0) cnt=0;
  const int K = Kp[0];
  for (int it=0; it<K; ++it){
    float m=-3.0e38f; int mi=0;
    #pragma unroll
    for (int r=0;r<8;++r){ if (v[r]>m){m=v[r]; mi=r;} }
    mi += j*8;
    #pragma unroll
    for (int o=32;o>=1;o>>=1){
      float om=__shfl_xor(m,o); int oi=__shfl_xor(mi,o);
      if (om>m){m=om;mi=oi;}
    }
    if ((j&63)==0){ wred[j>>6]=m; ired[j>>6]=mi; }
    __syncthreads();
    if (j==0){
      float bm=wred[0]; int bi=ired[0];
      #pragma unroll
      for (int w=1;w<4;++w) if (wred[w]>bm){bm=wred[w];bi=ired[w];}
      sh_kth=bm; sh_bi=bi;
      if (it==0) sh_max=bm;
    }
    __syncthreads();
    int sel = sh_bi - j*8;    // 0..7 iff this thread owns the winner
    #pragma unroll
    for (int r=0;r<8;++r) if (r==sel) v[r] = -3.0e38f;
  }
  const float kth=sh_kth, rmax=sh_max;
  #pragma unroll
  for (int r=0;r<8;++r){
    if (vo[r]>=kth){
      int p=atomicAdd(&cnt,1);
      if (p<256){ seli[p]=j*8+r; selw[p]=__expf(vo[r]-rmax); }
    }
  }
  __syncthreads();
  int c = cnt; if (c>256) c=256;
  {
    float p = (j<c)? selw[j] : 0.f;
    p = warp_sum64(p);
    if ((j&63)==0) wred[j>>6]=p;
    __syncthreads();
    if (j==0) sh_den = wred[0]+wred[1]+wred[2]+wred[3];
    __syncthreads();
  }
  float acc=0.f;
  for (int l=0;l<c;++l) acc += selw[l]*xs[(long)seli[l]*D_ + j];
  dynpre[(long)s*D_+j] = acc / sh_den;
}

// ---------------- hyper = sum_n ps[n] * reps[n] ----------------
__global__ void hyperwsum_kernel(const float* __restrict__ reps, const float* __restrict__ ps,
                                 float* __restrict__ hyper)
{
  long idx = (long)blockIdx.x*256+threadIdx.x;  // grid 2048
  hyper[idx] = ps[0]*reps[idx] + ps[1]*reps[(long)SD_+idx]
             + ps[2]*reps[2L*SD_+idx] + ps[3]*reps[3L*SD_+idx];
}

// ---------------- fusion ----------------
__global__ void fuse_kernel(const float* __restrict__ xs, const float* __restrict__ dyn,
                            const float* __restrict__ hyper, const float* __restrict__ beta,
                            float* __restrict__ fused)
{
  long idx = (long)blockIdx.x*256+threadIdx.x;  // grid 2048
  float b0=beta[0],b1=beta[1],b2=beta[2];
  float mx=fmaxf(b0,fmaxf(b1,b2));
  float e0=__expf(b0-mx),e1=__expf(b1-mx),e2=__expf(b2-mx);
  float inv=1.f/(e0+e1+e2);
  fused[idx] = e0*inv*xs[idx] + e1*inv*dyn[idx] + e2*inv*hyper[idx];
}

// ---------------- head ----------------
__global__ void head_kernel(const float* __restrict__ hh1, const float* __restrict__ Wm2,
                            const float* __restrict__ bm2, float* __restrict__ out)
{
  int r = blockIdx.x*32 + (threadIdx.x>>3);   // grid 64
  int sub = threadIdx.x&7;
  const float* hp = hh1 + (long)r*D_;
  float acc=0.f;
  for (int c=sub;c<D_;c+=8) acc += hp[c]*Wm2[c];
  acc += __shfl_xor(acc,1); acc += __shfl_xor(acc,2); acc += __shfl_xor(acc,4);
  if (sub==0) out[r]=acc+bm2[0];
}

// ---------------- launch ----------------
extern "C" void kernel_launch(void* const* d_in, const int* in_sizes, int n_in,
                              void* d_out, int out_size, void* d_ws, size_t ws_size,
                              hipStream_t stream)
{
  (void)in_sizes;(void)n_in;(void)out_size;(void)ws_size;
  const float* x        =(const float*)d_in[0];
  const float* snapshot =(const float*)d_in[1];
  const float* ps       =(const float*)d_in[2];
  const float* beta     =(const float*)d_in[3];
  const float* Wemb=(const float*)d_in[4];  const float* bemb=(const float*)d_in[5];
  const float* Wq  =(const float*)d_in[6];  const float* bq  =(const float*)d_in[7];
  const float* Wk  =(const float*)d_in[8];  const float* bk  =(const float*)d_in[9];
  const float* Wv  =(const float*)d_in[10]; const float* bv  =(const float*)d_in[11];
  const float* Wo  =(const float*)d_in[12]; const float* bo  =(const float*)d_in[13];
  const float* ln1g=(const float*)d_in[14]; const float* ln1b=(const float*)d_in[15];
  const float* Wint=(const float*)d_in[16]; const float* bint=(const float*)d_in[17];
  const float* Wmix=(const float*)d_in[18]; const float* bmix=(const float*)d_in[19];
  const float* ln2g=(const float*)d_in[20]; const float* ln2b=(const float*)d_in[21];
  const float* Wt  =(const float*)d_in[22]; const float* bt  =(const float*)d_in[23];
  const float* vt  =(const float*)d_in[24];
  const float* Wh1 =(const float*)d_in[25]; const float* bh1 =(const float*)d_in[26];
  const float* filt1=(const float*)d_in[27];
  const float* Wh2 =(const float*)d_in[28]; const float* bh2 =(const float*)d_in[29];
  const float* filt2=(const float*)d_in[30];
  const float* Wa  =(const float*)d_in[31]; const float* Wb  =(const float*)d_in[32];
  const float* Wg  =(const float*)d_in[33]; const float* bg  =(const float*)d_in[34];
  const float* Wm1 =(const float*)d_in[35]; const float* bm1 =(const float*)d_in[36];
  const float* Wm2 =(const float*)d_in[37]; const float* bm2 =(const float*)d_in[38];
  const int* numedges=(const int*)d_in[39];
  float* out=(float*)d_out;

  // ---- workspace layout (floats). Peak ~46.7 MB (unchanged). ----
  float* w = (float*)d_ws;
  // region [0 .. 4194304): overlays (stream-ordered): pe -> repsb -> sim
  float* pe    = w;
  float* repsb = w;
  float* sim   = w;
  float* P     = w + 4194304;            // NS*E*D = 131072
  float* Dv    = P + 131072;             // 8192
  float* De    = Dv + 8192;              // 512
  int*   ecnt  = (int*)(De + 512);       // 512
  int*   scnt  = ecnt + 512;             // 8192
  int*   ei    = scnt + 8192;            // 131072 (NS*E*256)
  float* ev    = (float*)(ei + 131072);  // 131072
  int*   si    = (int*)(ev + 131072);    // 262144 (NS*S*32)
  float* sv    = (float*)(si + 262144);  // 262144  -> ends at 5129216
  short* pk2   = (short*)(w + PK2BASE);  // 6 tail-GEMM weights, 1.5MB, ends < 6431232
  float* xs    = w + 6431232;
  float* hyper = xs + SD_;
  float* bufA  = hyper + SD_;            // NS*SD
  float* bufB  = bufA + 4*SD_;           // NS*SD
  float* p1    = bufA;
  float* q1    = bufA + SD_;
  float* dynpre= bufA + 2*SD_;
  float* dyn   = bufA + 3*SD_;
  float* fused = bufB;
  float* hh1   = bufB + SD_;
  short* pkc   = (short*)(w + PKBASE);   // 2MB combined packed weights

  hipMemsetAsync(De, 0, (size_t)NS_*E_*sizeof(float), stream);
  pe_kernel<<<64,256,0,stream>>>(pe);
  pack_all<<<dim3(256,14),256,0,stream>>>(Wq,Wk,Wv,Wo,Wint,Wt,Wmix,
                                          Wh1,Wh2,Wa,Wb,Wg,Wm1,pkc,pk2);

  stageA_kernel<<<S_,512,0,stream>>>(x,pe,Wemb,bemb,bq,bk,bv,bo,
                                     ln1g,ln1b,bint,bmix,ln2g,ln2b,bt,vt,
                                     pkc,xs);
  hg_deg<<<dim3(32,NS_),256,0,stream>>>(snapshot,Dv,De);
  build_ecsr<<<dim3(E_,NS_),256,0,stream>>>(snapshot,Dv,ei,ev,ecnt);
  build_scsr<<<dim3(8,NS_),256,0,stream>>>(snapshot,Dv,De,si,sv,scnt);

  auto applyA=[&](const float* M, long mz,
                  const float* X1, long x1z, float c1,
                  const float* X2, long x2z, float c2, float c3,
                  const float* filt, int uf, float* outb){
    hg_p1<<<dim3(E_,NS_),256,0,stream>>>(ei,ev,ecnt,M,mz,P);
    hg_p2<<<dim3(S_/8,NS_),256,0,stream>>>(si,sv,scnt,P,X1,x1z,c1,X2,x2z,c2,c3,filt,uf,outb);
  };

  // ---- wavelet hypergraph conv, layer 1 ----
  applyA(xs,0,     xs,0,1.f,    nullptr,0,0.f,  -1.f,  nullptr,0, bufA);  // t1 = L z
  applyA(bufA,SD_, xs,0,1.f,    bufA,SD_,1.5f,  -0.5f, filt1,1,   bufB);  // y0
  applyA(bufB,SD_, bufB,SD_,1.f, nullptr,0,0.f, -1.f,  nullptr,0, bufA);  // t3
  applyA(bufA,SD_, bufB,SD_,1.f, bufA,SD_,-0.5f,-0.5f, nullptr,0, bufA);  // p
  gemm_pk<<<128,256,0,stream>>>(bufA, pk2+PKH1, bufB, bh1, 2);   // r1 (M=NS*S flattened)

  // ---- layer 2 ----
  applyA(bufB,SD_, bufB,SD_,1.f, nullptr,0,0.f, -1.f,  nullptr,0, bufA);
  applyA(bufA,SD_, bufB,SD_,1.f, bufA,SD_,1.5f, -0.5f, filt2,1,   bufB);
  applyA(bufB,SD_, bufB,SD_,1.f, nullptr,0,0.f, -1.f,  nullptr,0, bufA);
  applyA(bufA,SD_, bufB,SD_,1.f, bufA,SD_,-0.5f,-0.5f, nullptr,0, bufA);
  gemm_pk<<<128,256,0,stream>>>(bufA, pk2+PKH2, repsb, bh2, 0);
  hyperwsum_kernel<<<2048,256,0,stream>>>(repsb,ps,hyper);

  // ---- dynamic graph ----
  gemm_pk<<<32,256,0,stream>>>(xs, pk2+PKA, p1, nullptr, 0);
  gemm_pk<<<32,256,0,stream>>>(xs, pk2+PKB, q1, nullptr, 0);
  gemm_nt_pk<<<dim3(32,32),256,0,stream>>>(p1,q1,sim,0.0625f);
  topk_gather<<<S_,256,0,stream>>>(sim,xs,numedges,dynpre);
  gemm_pk<<<32,256,0,stream>>>(dynpre, pk2+PKG, dyn, bg, 1);

  // ---- fusion + head ----
  fuse_kernel<<<2048,256,0,stream>>>(xs,dyn,hyper,beta,fused);
  gemm_pk<<<32,256,0,stream>>>(fused, pk2+PKM1, hh1, bm1, 1);
  head_kernel<<<64,256,0,stream>>>(hh1,Wm2,bm2,out);
}

// Round 11
// 1433.342 us; speedup vs baseline: 1.0800x; 1.0800x over previous
//
#include <hip/hip_runtime.h>
#include <math.h>

#define S_ 2048
#define T_ 64
#define F_ 16
#define D_ 256
#define NS_ 4
#define E_ 128
#define H_ 8
#define SD_ (S_*D_)
#define PS 264   // packed h plane row stride (shorts)

// packed-weight combined buffer (shorts), round-contiguous
#define PK_ATT 0         // 4hp x 8kt x 12288 shorts (Qh,Ql,Kh,Kl,Vh,Vl x 2048)
#define PK_WO  393216    // 8 kt-tiles x 16384 (hi 8192 | lo 8192)
#define PK_WI  524288
#define PK_WT  655360
#define PK_WM  786432    // 16 kt-tiles
#define PKBASE 11674112  // float offset in ws where pkc starts (2MB)
// secondary packed buffer (tail GEMM weights), lives in dead ws region
#define PK2BASE 5242880  // float offset; 6 x 131072 shorts = 1.5MB
#define PKH1 0
#define PKH2 131072
#define PKA  262144
#define PKB  393216
#define PKG  524288
#define PKM1 655360

typedef __attribute__((ext_vector_type(8))) short bf16x8;
typedef __attribute__((ext_vector_type(4))) float f32x4;

// ---------------- helpers ----------------
__device__ __forceinline__ float warp_sum64(float v){
  #pragma unroll
  for (int o=32;o>=1;o>>=1) v += __shfl_xor(v,o);
  return v;
}
__device__ __forceinline__ float warp_max64(float v){
  #pragma unroll
  for (int o=32;o>=1;o>>=1) v = fmaxf(v,__shfl_xor(v,o));
  return v;
}
__device__ __forceinline__ float softplus_f(float v){
  return fmaxf(v,0.f) + log1pf(__expf(-fabsf(v)));
}
__device__ __forceinline__ float tanh_f(float v){
  float t = __expf(-2.f*fabsf(v));
  float r = (1.f-t)/(1.f+t);
  return copysignf(r, v);
}
// split fp32 into bf16 hi + bf16 lo (RNE)
__device__ __forceinline__ void splitf(float f, short& h, short& l){
  unsigned u = __float_as_uint(f);
  unsigned hb = (u + 0x7FFFu + ((u>>16)&1u)) >> 16;
  float fl = f - __uint_as_float(hb<<16);
  unsigned v = __float_as_uint(fl);
  unsigned lb = (v + 0x7FFFu + ((v>>16)&1u)) >> 16;
  h = (short)hb; l = (short)lb;
}
__device__ __forceinline__ f32x4 mfma3(bf16x8 ah, bf16x8 al, bf16x8 bh, bf16x8 bl, f32x4 c){
  c = __builtin_amdgcn_mfma_f32_16x16x32_bf16(al, bh, c, 0,0,0);
  c = __builtin_amdgcn_mfma_f32_16x16x32_bf16(ah, bl, c, 0,0,0);
  c = __builtin_amdgcn_mfma_f32_16x16x32_bf16(ah, bh, c, 0,0,0);
  return c;
}
__device__ __forceinline__ void afrag_f32(const float* base, int stride, int rbase, int ks, int lane, bf16x8& hi, bf16x8& lo){
  const float* p = base + (rbase + (lane&15))*stride + ks + ((lane>>4)<<3);
  #pragma unroll
  for (int jj=0;jj<8;++jj){ short h,l; splitf(p[jj],h,l); hi[jj]=h; lo[jj]=l; }
}
__device__ __forceinline__ bf16x8 afrag_pk(const short* plane, int rbase, int ks, int lane){
  return *(const bf16x8*)(plane + (rbase + (lane&15))*PS + ks + ((lane>>4)<<3));
}
__device__ __forceinline__ void bfrag_pk(const unsigned* pk, int tile, int lane, bf16x8& hi, bf16x8& lo){
  const unsigned* p = pk + (((tile<<6) + lane)<<3);
  #pragma unroll
  for (int jj=0;jj<8;++jj){ unsigned u=p[jj]; hi[jj]=(short)(u & 0xffffu); lo[jj]=(short)(u>>16); }
}
__device__ __forceinline__ void store_h(short* Hh, short* Hl, int r, int c, float f){
  short h,l; splitf(f,h,l);
  Hh[r*PS+c]=h; Hl[r*PS+c]=l;
}
__device__ __forceinline__ float load_h(const short* Hh, const short* Hl, int r, int c){
  int idx=r*PS+c;
  return __uint_as_float(((unsigned)(unsigned short)Hh[idx])<<16)
       + __uint_as_float(((unsigned)(unsigned short)Hl[idx])<<16);
}

// ---------------- weight packing (all 13 targets in one launch) ----------------
__global__ void pack_all(const float* __restrict__ Wq, const float* __restrict__ Wk,
                         const float* __restrict__ Wv, const float* __restrict__ Wo,
                         const float* __restrict__ Wint, const float* __restrict__ Wt,
                         const float* __restrict__ Wmix,
                         const float* __restrict__ Wh1, const float* __restrict__ Wh2,
                         const float* __restrict__ Wa, const float* __restrict__ Wb,
                         const float* __restrict__ Wg, const float* __restrict__ Wm1,
                         short* __restrict__ pkc, short* __restrict__ pk2){
  int y = blockIdx.y;
  int i = blockIdx.x*256 + threadIdx.x;   // 65536
  if (y < 3){
    const float* W = (y==0)?Wq:((y==1)?Wk:Wv);
    int jj=i&7, n=(i>>3)&15, q=(i>>7)&3, ntg=(i>>9)&15, kt=i>>13;
    float f = W[(kt*32 + q*8 + jj)*256 + (ntg*16+n)];
    short h,l; splitf(f,h,l);
    int hp = ntg>>2, ntl = ntg&3;
    int base = ((hp*8+kt)*6 + y*2)*2048;
    int local = ntl*512 + (q*16+n)*8 + jj;
    short* dst = pkc + PK_ATT;
    dst[base+local] = h;
    dst[base+2048+local] = l;
  } else {
    const float* W; short* dst; int ib = i;
    if (y==3){W=Wo;   dst=pkc+PK_WO;}
    else if (y==4){W=Wint; dst=pkc+PK_WI;}
    else if (y==5){W=Wt;   dst=pkc+PK_WT;}
    else if (y==6){W=Wmix; dst=pkc+PK_WM;}
    else if (y==7){W=Wmix; dst=pkc+PK_WM; ib = i + 65536;}
    else if (y==8){W=Wh1;  dst=pk2+PKH1;}
    else if (y==9){W=Wh2;  dst=pk2+PKH2;}
    else if (y==10){W=Wa;  dst=pk2+PKA;}
    else if (y==11){W=Wb;  dst=pk2+PKB;}
    else if (y==12){W=Wg;  dst=pk2+PKG;}
    else          {W=Wm1;  dst=pk2+PKM1;}
    int jj=ib&7, n=(ib>>3)&15, q=(ib>>7)&3, ntg=(ib>>9)&15, kt=ib>>13;
    float f = W[(kt*32 + q*8 + jj)*256 + (ntg*16+n)];
    short h,l; splitf(f,h,l);
    int dl = kt*16384 + ntg*512 + (q*16+n)*8 + jj;
    dst[dl] = h; dst[dl+8192] = l;
  }
}

// ---------------- positional encoding ----------------
__global__ void pe_kernel(float* __restrict__ pe){
  int i = blockIdx.x*256 + threadIdx.x;       // grid 64 -> 16384
  int t = i >> 8, d = i & 255;
  int ii = d >> 1;
  float w = __expf(-(float)ii * (logf(10000.f)/128.f));
  float ang = (float)t * w;
  pe[i] = (d & 1) ? cosf(ang) : sinf(ang);
}

// ---------------- stage A (R6 structure: best measured) ----------------
// LDS: planes 2x33792 + smem 85504 = 153088 B -> 1 block/CU, 8 waves (2/SIMD)
__launch_bounds__(512,1)
__global__ void stageA_kernel(
    const float* __restrict__ x, const float* __restrict__ pe,
    const float* __restrict__ Wemb, const float* __restrict__ bemb,
    const float* __restrict__ bq, const float* __restrict__ bk, const float* __restrict__ bv,
    const float* __restrict__ bo,
    const float* __restrict__ ln1g, const float* __restrict__ ln1b,
    const float* __restrict__ bint,
    const float* __restrict__ bmix,
    const float* __restrict__ ln2g, const float* __restrict__ ln2b,
    const float* __restrict__ bt,
    const float* __restrict__ vt,
    const short* __restrict__ pkc,
    float* __restrict__ xs)
{
  __shared__ __attribute__((aligned(16))) short hbh[64*PS];   // 33792 B
  __shared__ __attribute__((aligned(16))) short hbl[64*PS];   // 33792 B
  __shared__ __attribute__((aligned(16))) char smem[85504];

  short*    wst   = (short*)smem;                      // QKV staging 24KB
  unsigned* k2f2  = (unsigned*)smem;                   // overlay: 2 heads x 2048 u32
  unsigned* v2f2  = (unsigned*)(smem + 16384);         // 16KB
  float*    qb2   = (float*)(smem + 32768);            // [64][68] q / o_h
  float*    scb2  = (float*)(smem + 50176);            // 2 x [64][68] probs
  float*    poolb = (float*)smem;                      // overlay post-attention

  const int j  = threadIdx.x;
  const int s  = blockIdx.x;
  const int w  = j >> 6;            // wave 0..7
  const int lane = j & 63;
  const int m_ = lane & 15, qd = lane >> 4;
  const int rg2 = w >> 1, par = w & 1;
  const int rbase = rg2*16;
  const int rv = w*8;
  const int c0 = lane;

  // ---- stage x[s] ----
  {
    float* xb = (float*)smem;
    const float* xp = x + (long)s*T_*F_;
    for (int i=j; i<T_*F_; i+=512) xb[i] = xp[i];
  }
  __syncthreads();

  // ---- embedding + PE -> packed planes ----
  {
    const float* xb = (const float*)smem;
    float acc[8][4];
    #pragma unroll
    for (int r=0;r<8;++r){acc[r][0]=0;acc[r][1]=0;acc[r][2]=0;acc[r][3]=0;}
    #pragma unroll
    for (int k=0;k<F_;++k){
      float w0=Wemb[k*D_+c0], w1=Wemb[k*D_+c0+64], w2=Wemb[k*D_+c0+128], w3=Wemb[k*D_+c0+192];
      #pragma unroll
      for (int r=0;r<8;++r){
        float hv = xb[(rv+r)*F_+k];
        acc[r][0]+=hv*w0; acc[r][1]+=hv*w1; acc[r][2]+=hv*w2; acc[r][3]+=hv*w3;
      }
    }
    float b0=bemb[c0],b1=bemb[c0+64],b2=bemb[c0+128],b3=bemb[c0+192];
    __syncthreads();
    #pragma unroll
    for (int r=0;r<8;++r){
      int t = rv+r;
      store_h(hbh,hbl,t,c0,     acc[r][0]+b0+pe[t*D_+c0]);
      store_h(hbh,hbl,t,c0+64,  acc[r][1]+b1+pe[t*D_+c0+64]);
      store_h(hbh,hbl,t,c0+128, acc[r][2]+b2+pe[t*D_+c0+128]);
      store_h(hbh,hbl,t,c0+192, acc[r][3]+b3+pe[t*D_+c0+192]);
    }
  }
  __syncthreads();

  // ---- hoist QKV A-fragments ----
  bf16x8 AH[8], AL[8];
  #pragma unroll
  for (int kt=0;kt<8;++kt){
    AH[kt] = afrag_pk(hbh, rbase, kt*32, lane);
    AL[kt] = afrag_pk(hbl, rbase, kt*32, lane);
  }

  const float rs = 0.17677669529663687f;  // 1/sqrt(32)
  f32x4 co[8];
  #pragma unroll
  for (int t=0;t<8;++t) co[t] = (f32x4){0.f,0.f,0.f,0.f};

  // ---- attention: head pairs, head = parity ----
  for (int hp=0; hp<4; ++hp){
    f32x4 qa[2],ka[2],va[2];
    #pragma unroll
    for (int t=0;t<2;++t){
      qa[t]=(f32x4){0.f,0.f,0.f,0.f};
      ka[t]=(f32x4){0.f,0.f,0.f,0.f};
      va[t]=(f32x4){0.f,0.f,0.f,0.f};
    }
    bf16x8 pre[3];
    {
      const short* b0 = pkc + PK_ATT + (hp*8)*12288;
      #pragma unroll
      for (int r=0;r<3;++r) pre[r] = *(const bf16x8*)(b0 + (j+r*512)*8);
    }
    for (int kt=0; kt<8; ++kt){
      __syncthreads();
      #pragma unroll
      for (int r=0;r<3;++r) *(bf16x8*)(wst + (j+r*512)*8) = pre[r];
      __syncthreads();
      if (kt<7){
        const short* nb = pkc + PK_ATT + (hp*8+kt+1)*12288;
        #pragma unroll
        for (int r=0;r<3;++r) pre[r] = *(const bf16x8*)(nb + (j+r*512)*8);
      }
      bf16x8 ah = AH[kt], al = AL[kt];
      #pragma unroll
      for (int t=0;t<2;++t){
        int ntl = par*2+t;
        bf16x8 bh,bl;
        bh = *(bf16x8*)(wst +         ntl*512 + lane*8);
        bl = *(bf16x8*)(wst + 2048  + ntl*512 + lane*8);
        qa[t]=mfma3(ah,al,bh,bl,qa[t]);
        bh = *(bf16x8*)(wst + 4096  + ntl*512 + lane*8);
        bl = *(bf16x8*)(wst + 6144  + ntl*512 + lane*8);
        ka[t]=mfma3(ah,al,bh,bl,ka[t]);
        bh = *(bf16x8*)(wst + 8192  + ntl*512 + lane*8);
        bl = *(bf16x8*)(wst + 10240 + ntl*512 + lane*8);
        va[t]=mfma3(ah,al,bh,bl,va[t]);
      }
    }
    __syncthreads();   // QKV reads done; epilogue overwrites staging region
    // epilogue: q->qb2 (scaled), k/v -> packed B-frag LDS
    #pragma unroll
    for (int t=0;t<2;++t){
      int ntg = par*2+t;
      #pragma unroll
      for (int r=0;r<4;++r){
        int trow = rbase + qd*4 + r;
        int pcp = ntg*16 + m_;
        int head = pcp >> 5;
        int cp = pcp & 31;
        int col = hp*64 + pcp;
        qb2[trow*68 + pcp] = (qa[t][r] + bq[col]) * rs;
        short hS,lS;
        float kv2 = ka[t][r] + bk[col];
        splitf(kv2,hS,lS);
        k2f2[head*2048 + (((trow>>4)*4 + (cp>>3))*16 + (trow&15))*8 + (cp&7)]
            = (unsigned)(unsigned short)hS | ((unsigned)(unsigned short)lS<<16);
        float vv2 = va[t][r] + bv[col];
        splitf(vv2,hS,lS);
        v2f2[head*2048 + ((((trow>>5)*2 + (cp>>4))*4 + ((trow>>3)&3))*16 + (cp&15))*8 + (trow&7)]
            = (unsigned)(unsigned short)hS | ((unsigned)(unsigned short)lS<<16);
      }
    }
    __syncthreads();   // k2f2/v2f2/qb2 visible
    // ---- scores + softmax (head = par) ----
    float* scb = scb2 + par*4352;
    {
      bf16x8 ah,al;
      afrag_f32(qb2, 68, rbase, par*32, lane, ah, al);
      f32x4 sc4[4];
      #pragma unroll
      for (int nt=0;nt<4;++nt){
        bf16x8 bh,bl; bfrag_pk(k2f2 + par*2048, nt, lane, bh, bl);
        sc4[nt] = mfma3(ah,al,bh,bl,(f32x4){0.f,0.f,0.f,0.f});
      }
      #pragma unroll
      for (int r=0;r<4;++r){
        float mx = fmaxf(fmaxf(sc4[0][r],sc4[1][r]),fmaxf(sc4[2][r],sc4[3][r]));
        #pragma unroll
        for (int o=8;o>=1;o>>=1) mx = fmaxf(mx, __shfl_xor(mx,o));
        float es = 0.f;
        #pragma unroll
        for (int nt=0;nt<4;++nt){ float e=__expf(sc4[nt][r]-mx); sc4[nt][r]=e; es+=e; }
        #pragma unroll
        for (int o=8;o>=1;o>>=1) es += __shfl_xor(es,o);
        float inv = 1.f/es;
        int trow = rbase + qd*4 + r;
        #pragma unroll
        for (int nt=0;nt<4;++nt) scb[trow*68 + nt*16 + m_] = sc4[nt][r]*inv;
      }
    }
    // ---- o = P @ V (head = par) ----
    {
      f32x4 oa[2];
      oa[0]=(f32x4){0.f,0.f,0.f,0.f}; oa[1]=(f32x4){0.f,0.f,0.f,0.f};
      #pragma unroll
      for (int kt=0;kt<2;++kt){
        bf16x8 ah2,al2; afrag_f32(scb, 68, rbase, kt*32, lane, ah2, al2);
        #pragma unroll
        for (int nt=0;nt<2;++nt){
          bf16x8 bh,bl; bfrag_pk(v2f2 + par*2048, kt*2+nt, lane, bh, bl);
          oa[nt]=mfma3(ah2,al2,bh,bl,oa[nt]);
        }
      }
      #pragma unroll
      for (int nt=0;nt<2;++nt){
        #pragma unroll
        for (int r=0;r<4;++r)
          qb2[(rbase+qd*4+r)*68 + par*32 + nt*16 + m_] = oa[nt][r];
      }
    }
    __syncthreads();   // PV writes to qb2 visible (Wo reads both heads' cols)
    // ---- Wo accumulate: B direct from global ----
    for (int ks=0; ks<2; ++ks){
      bf16x8 ah,al; afrag_f32(qb2, 68, rbase, ks*32, lane, ah, al);
      const short* wob = pkc + PK_WO + (hp*2+ks)*16384 + lane*8;
      #pragma unroll
      for (int t=0;t<8;++t){
        int ntg = 2*t+par;
        bf16x8 bh = *(const bf16x8*)(wob + ntg*512);
        bf16x8 bl = *(const bf16x8*)(wob + 8192 + ntg*512);
        co[t]=mfma3(ah,al,bh,bl,co[t]);
      }
    }
  }

  // ---- residual + bo -> planes ----
  #pragma unroll
  for (int t=0;t<8;++t){
    int cc = (2*t+par)*16+m_;
    float bov = bo[cc];
    #pragma unroll
    for (int r=0;r<4;++r){
      int row = rbase+qd*4+r;
      store_h(hbh,hbl,row,cc, load_h(hbh,hbl,row,cc) + co[t][r] + bov);
    }
  }
  __syncthreads();

  // ---- LN1 ----
  {
    float g0=ln1g[c0],g1=ln1g[c0+64],g2=ln1g[c0+128],g3=ln1g[c0+192];
    float bb0=ln1b[c0],bb1=ln1b[c0+64],bb2=ln1b[c0+128],bb3=ln1b[c0+192];
    for (int rr=0;rr<8;++rr){
      int t=rv+rr;
      float v0=load_h(hbh,hbl,t,c0),    v1=load_h(hbh,hbl,t,c0+64);
      float v2=load_h(hbh,hbl,t,c0+128),v3=load_h(hbh,hbl,t,c0+192);
      float sm=warp_sum64(v0+v1+v2+v3);
      float sq=warp_sum64(v0*v0+v1*v1+v2*v2+v3*v3);
      float mean=sm*(1.f/256.f);
      float inv=rsqrtf(fmaxf(sq*(1.f/256.f)-mean*mean,0.f)+1e-5f);
      store_h(hbh,hbl,t,c0,    (v0-mean)*inv*g0+bb0);
      store_h(hbh,hbl,t,c0+64, (v1-mean)*inv*g1+bb1);
      store_h(hbh,hbl,t,c0+128,(v2-mean)*inv*g2+bb2);
      store_h(hbh,hbl,t,c0+192,(v3-mean)*inv*g3+bb3);
    }
  }
  __syncthreads();

  // ---- post GEMMs: M=64/wave, nt={2w,2w+1}, B direct from global w/ prefetch ----
  auto loadB=[&](bf16x8* d, const short* base, int kt){
    const short* p = base + kt*16384 + lane*8;
    d[0]=*(const bf16x8*)(p + (2*w)*512);
    d[1]=*(const bf16x8*)(p + 8192 + (2*w)*512);
    d[2]=*(const bf16x8*)(p + (2*w+1)*512);
    d[3]=*(const bf16x8*)(p + 8192 + (2*w+1)*512);
  };
  const short* BM = pkc + PK_WM;
  const short* BI = pkc + PK_WI;
  const short* BT = pkc + PK_WT;

  f32x4 az[4][2], ai[4][2];
  #pragma unroll
  for (int rt=0;rt<4;++rt){
    az[rt][0]=(f32x4){0.f,0.f,0.f,0.f}; az[rt][1]=(f32x4){0.f,0.f,0.f,0.f};
    ai[rt][0]=(f32x4){0.f,0.f,0.f,0.f}; ai[rt][1]=(f32x4){0.f,0.f,0.f,0.f};
  }
  bf16x8 cb[4], nb[4];
  loadB(cb, BM, 0);
  // Wmix part1 (A = h)
  for (int kt=0; kt<8; ++kt){
    if (kt<7) loadB(nb, BM, kt+1); else loadB(nb, BI, 0);
    #pragma unroll
    for (int rt=0;rt<4;++rt){
      bf16x8 ah = afrag_pk(hbh, rt*16, kt*32, lane);
      bf16x8 al = afrag_pk(hbl, rt*16, kt*32, lane);
      az[rt][0]=mfma3(ah,al,cb[0],cb[1],az[rt][0]);
      az[rt][1]=mfma3(ah,al,cb[2],cb[3],az[rt][1]);
    }
    #pragma unroll
    for (int r=0;r<4;++r) cb[r]=nb[r];
  }
  // Wint (A = h)
  for (int kt=0; kt<8; ++kt){
    if (kt<7) loadB(nb, BI, kt+1); else loadB(nb, BM, 8);
    #pragma unroll
    for (int rt=0;rt<4;++rt){
      bf16x8 ah = afrag_pk(hbh, rt*16, kt*32, lane);
      bf16x8 al = afrag_pk(hbl, rt*16, kt*32, lane);
      ai[rt][0]=mfma3(ah,al,cb[0],cb[1],ai[rt][0]);
      ai[rt][1]=mfma3(ah,al,cb[2],cb[3],ai[rt][1]);
    }
    #pragma unroll
    for (int r=0;r<4;++r) cb[r]=nb[r];
  }
  __syncthreads();
  // intensity -> planes
  #pragma unroll
  for (int rt=0;rt<4;++rt){
    #pragma unroll
    for (int t=0;t<2;++t){
      int col=(2*w+t)*16+m_;
      float bb=bint[col];
      #pragma unroll
      for (int r=0;r<4;++r)
        store_h(hbh,hbl, rt*16+qd*4+r, col, softplus_f(ai[rt][t][r]+bb));
    }
  }
  __syncthreads();
  // Wmix part2 (A = intensity, B tiles 8..15)
  for (int kt=0; kt<8; ++kt){
    if (kt<7) loadB(nb, BM, kt+9); else loadB(nb, BT, 0);
    #pragma unroll
    for (int rt=0;rt<4;++rt){
      bf16x8 ah = afrag_pk(hbh, rt*16, kt*32, lane);
      bf16x8 al = afrag_pk(hbl, rt*16, kt*32, lane);
      az[rt][0]=mfma3(ah,al,cb[0],cb[1],az[rt][0]);
      az[rt][1]=mfma3(ah,al,cb[2],cb[3],az[rt][1]);
    }
    #pragma unroll
    for (int r=0;r<4;++r) cb[r]=nb[r];
  }
  __syncthreads();
  // z = relu -> planes
  #pragma unroll
  for (int rt=0;rt<4;++rt){
    #pragma unroll
    for (int t=0;t<2;++t){
      int col=(2*w+t)*16+m_;
      float bb=bmix[col];
      #pragma unroll
      for (int r=0;r<4;++r)
        store_h(hbh,hbl, rt*16+qd*4+r, col, fmaxf(az[rt][t][r]+bb,0.f));
    }
  }
  __syncthreads();
  // ---- LN2 ----
  {
    float g0=ln2g[c0],g1=ln2g[c0+64],g2=ln2g[c0+128],g3=ln2g[c0+192];
    float bb0=ln2b[c0],bb1=ln2b[c0+64],bb2=ln2b[c0+128],bb3=ln2b[c0+192];
    for (int rr=0;rr<8;++rr){
      int t=rv+rr;
      float v0=load_h(hbh,hbl,t,c0),    v1=load_h(hbh,hbl,t,c0+64);
      float v2=load_h(hbh,hbl,t,c0+128),v3=load_h(hbh,hbl,t,c0+192);
      float sm=warp_sum64(v0+v1+v2+v3);
      float sq=warp_sum64(v0*v0+v1*v1+v2*v2+v3*v3);
      float mean=sm*(1.f/256.f);
      float inv=rsqrtf(fmaxf(sq*(1.f/256.f)-mean*mean,0.f)+1e-5f);
      store_h(hbh,hbl,t,c0,    (v0-mean)*inv*g0+bb0);
      store_h(hbh,hbl,t,c0+64, (v1-mean)*inv*g1+bb1);
      store_h(hbh,hbl,t,c0+128,(v2-mean)*inv*g2+bb2);
      store_h(hbh,hbl,t,c0+192,(v3-mean)*inv*g3+bb3);
    }
  }
  __syncthreads();
  // ---- Wt: u = tanh(h@Wt+bt), pooled ----
  {
    f32x4 at4[4][2];
    #pragma unroll
    for (int rt=0;rt<4;++rt){
      at4[rt][0]=(f32x4){0.f,0.f,0.f,0.f}; at4[rt][1]=(f32x4){0.f,0.f,0.f,0.f};
    }
    for (int kt=0; kt<8; ++kt){
      if (kt<7) loadB(nb, BT, kt+1);
      #pragma unroll
      for (int rt=0;rt<4;++rt){
        bf16x8 ah = afrag_pk(hbh, rt*16, kt*32, lane);
        bf16x8 al = afrag_pk(hbl, rt*16, kt*32, lane);
        at4[rt][0]=mfma3(ah,al,cb[0],cb[1],at4[rt][0]);
        at4[rt][1]=mfma3(ah,al,cb[2],cb[3],at4[rt][1]);
      }
      #pragma unroll
      for (int r=0;r<4;++r) cb[r]=nb[r];
    }
    #pragma unroll
    for (int rt=0;rt<4;++rt){
      #pragma unroll
      for (int r=0;r<4;++r){
        int row = rt*16+qd*4+r;
        float p = 0.f;
        #pragma unroll
        for (int t=0;t<2;++t){
          int col=(2*w+t)*16+m_;
          p += tanh_f(at4[rt][t][r]+bt[col])*vt[col];
        }
        p += __shfl_xor(p,1); p += __shfl_xor(p,2);
        p += __shfl_xor(p,4); p += __shfl_xor(p,8);
        if (m_==0) poolb[w*64+row] = p;
      }
    }
  }
  __syncthreads();
  if (j < 64){
    float v = 0.f;
    #pragma unroll
    for (int ww=0;ww<8;++ww) v += poolb[ww*64+j];
    float m = warp_max64(v);
    float e = __expf(v-m);
    float ssum = warp_sum64(e);
    poolb[512+j] = e/ssum;
  }
  __syncthreads();
  if (j < 256){
    float acc=0.f;
    #pragma unroll 8
    for (int t=0;t<T_;++t) acc += poolb[512+t]*load_h(hbh,hbl,t,j);
    xs[(long)s*D_+j] = acc;
  }
}

// ---------------- hypergraph degrees ----------------
__global__ void hg_deg(const float* __restrict__ Hinc, float* __restrict__ Dv, float* __restrict__ De){
  const int n = blockIdx.y, s0 = blockIdx.x*64;   // grid (32, NS)
  const float* Hp = Hinc + (long)n*S_*E_;
  const int j = threadIdx.x;
  {
    int r = j>>2, q = j&3;
    const float* rp = Hp + (long)(s0+r)*E_ + q*32;
    float sm=0;
    #pragma unroll
    for (int e=0;e<32;++e) sm += rp[e];
    sm += __shfl_xor(sm,1); sm += __shfl_xor(sm,2);
    if (q==0) Dv[n*S_+s0+r]=sm+1e-6f;
  }
  if (j < E_){
    float cs=0;
    for (int ss=0;ss<64;++ss) cs += Hp[(long)(s0+ss)*E_+j];
    atomicAdd(&De[n*E_+j], cs);
  }
}

// ---------------- CSR builds (deterministic, ascending index order) ----------------
__global__ void build_ecsr(const float* __restrict__ snap, const float* __restrict__ Dv,
                           int* __restrict__ ei, float* __restrict__ ev, int* __restrict__ ecnt){
  __shared__ int cnts[257];
  const int e = blockIdx.x, n = blockIdx.y, t = threadIdx.x;
  const float* col = snap + (long)n*S_*E_ + e;
  int loc[8]; int c=0;
  #pragma unroll
  for (int r=0;r<8;++r){
    int s = t*8+r;
    if (col[(long)s*E_] != 0.f) loc[c++]=s;
  }
  cnts[t+1]=c;
  __syncthreads();
  if (t==0){ cnts[0]=0; for (int i=1;i<=256;++i) cnts[i]+=cnts[i-1]; }
  __syncthreads();
  int base = cnts[t];
  long eb = ((long)n*E_+e)*256;
  for (int k=0;k<c;++k){
    int pos = base+k;
    if (pos<256){ ei[eb+pos]=loc[k]; ev[eb+pos]=rsqrtf(Dv[n*S_+loc[k]]); }
  }
  if (t==255) ecnt[n*E_+e] = min(cnts[256],256);
}
__global__ void build_scsr(const float* __restrict__ snap, const float* __restrict__ Dv,
                           const float* __restrict__ De,
                           int* __restrict__ si, float* __restrict__ sv, int* __restrict__ scnt){
  const int s = blockIdx.x*256+threadIdx.x, n = blockIdx.y;
  const float* row = snap + ((long)n*S_+s)*E_;
  float vs = rsqrtf(Dv[n*S_+s]);
  long sb = ((long)n*S_+s)*32;
  int c=0;
  for (int e=0;e<E_;++e){
    if (row[e]!=0.f && c<32){
      si[sb+c]=e;
      sv[sb+c]=vs/(De[n*E_+e]+1e-6f);
      ++c;
    }
  }
  scnt[n*S_+s]=c;
}

// ---------------- sparse hypergraph apply (throughput-shaped) ----------------
__launch_bounds__(256,4)
__global__ void hg_p1(const int* __restrict__ ei, const float* __restrict__ ev,
                      const int* __restrict__ ecnt,
                      const float* __restrict__ M, long mz, float* __restrict__ P){
  __shared__ int sidx[256];
  __shared__ float sval[256];
  const int e = blockIdx.x, n = blockIdx.y, d = threadIdx.x;   // grid (E_, NS_)
  long eb = ((long)n*E_+e)*256;
  const int c = ecnt[n*E_+e];
  if (d < c){ sidx[d]=ei[eb+d]; sval[d]=ev[eb+d]; }
  __syncthreads();
  const float* Mp = M + (long)n*mz;
  float a0=0.f,a1=0.f,a2=0.f,a3=0.f;
  int i=0;
  for (; i+4<=c; i+=4){
    float m0 = Mp[(long)sidx[i+0]*D_+d];
    float m1 = Mp[(long)sidx[i+1]*D_+d];
    float m2 = Mp[(long)sidx[i+2]*D_+d];
    float m3 = Mp[(long)sidx[i+3]*D_+d];
    a0 += sval[i+0]*m0; a1 += sval[i+1]*m1;
    a2 += sval[i+2]*m2; a3 += sval[i+3]*m3;
  }
  for (; i<c; ++i) a0 += sval[i]*Mp[(long)sidx[i]*D_+d];
  P[((long)n*E_+e)*D_+d] = (a0+a1)+(a2+a3);
}
__launch_bounds__(256,4)
__global__ void hg_p2(const int* __restrict__ si, const float* __restrict__ sv,
                      const int* __restrict__ scnt, const float* __restrict__ P,
                      const float* __restrict__ X1, long x1z, float c1,
                      const float* __restrict__ X2, long x2z, float c2,
                      float c3, const float* __restrict__ filt, int usefilt,
                      float* __restrict__ out){
  __shared__ int sidx[8][32];
  __shared__ float sval[8][32];
  __shared__ int scc[8];
  const int s0 = blockIdx.x*8, n = blockIdx.y, d = threadIdx.x;  // grid (S_/8, NS_)
  {
    int k = d>>5, i = d&31;
    long sb = ((long)n*S_+s0+k)*32;
    sidx[k][i] = si[sb+i];
    sval[k][i] = sv[sb+i];
    if (i==0) scc[k] = scnt[n*S_+s0+k];
  }
  __syncthreads();
  const float* Pn = P + (long)n*E_*D_;
  #pragma unroll
  for (int k=0;k<8;++k){
    int s = s0+k;
    int c = scc[k];
    float acc=0.f;
    for (int i=0;i<c;++i) acc += sval[k][i]*Pn[(long)sidx[k][i]*D_+d];
    long li=(long)s*D_+d;
    float v=c3*acc;
    if (X1) v+=c1*X1[x1z*n+li];
    if (X2) v+=c2*X2[x2z*n+li];
    out[((long)n*S_+s)*D_+d]=(usefilt?filt[s]:1.f)*v;
  }
}

// ---------------- MFMA tail GEMM v2 (N-split): grid (M/64, 4) ----------------
// wave w: rows r0..+16, nt tiles blockIdx.y*4..+4. Output fp32 C or packed hi/lo planes.
__launch_bounds__(256,4)
__global__ void gemm_pk(const float* __restrict__ A, const short* __restrict__ Bpk,
                        float* __restrict__ C, short* __restrict__ Ch, short* __restrict__ Cl,
                        const float* __restrict__ bias, int act)
{
  const int j = threadIdx.x;
  const int w = j>>6, lane = j&63;
  const int m_ = lane&15, qd = lane>>4;
  const long r0 = (long)blockIdx.x*64 + w*16;
  const int nb = blockIdx.y*4;
  f32x4 acc[4];
  #pragma unroll
  for (int t=0;t<4;++t) acc[t]=(f32x4){0.f,0.f,0.f,0.f};
  #pragma unroll
  for (int kt=0; kt<8; ++kt){
    bf16x8 ah, al;
    {
      const float* p = A + (r0 + m_)*D_ + kt*32 + (qd<<3);
      #pragma unroll
      for (int jj=0;jj<8;++jj){ short h,l; splitf(p[jj],h,l); ah[jj]=h; al[jj]=l; }
    }
    const short* bp = Bpk + kt*16384 + lane*8;
    #pragma unroll
    for (int t=0;t<4;++t){
      bf16x8 bh = *(const bf16x8*)(bp + (nb+t)*512);
      bf16x8 bl = *(const bf16x8*)(bp + 8192 + (nb+t)*512);
      acc[t]=mfma3(ah,al,bh,bl,acc[t]);
    }
  }
  #pragma unroll
  for (int t=0;t<4;++t){
    int col = (nb+t)*16+m_;
    float bb = bias ? bias[col] : 0.f;
    #pragma unroll
    for (int r=0;r<4;++r){
      float v = acc[t][r]+bb;
      if (act==1) v=fmaxf(v,0.f);
      else if (act==2) v=(v>0.f)?v:0.1f*v;
      long idx = (r0+qd*4+r)*D_ + col;
      if (C) C[idx]=v;
      else { short h,l; splitf(v,h,l); Ch[idx]=h; Cl[idx]=l; }
    }
  }
}

// ---------------- MFMA NT GEMM on pre-packed planes: C = scale * A @ B^T ----------------
// A,B as bf16 hi/lo short planes [2048 x 256] row-major. grid (32,32), 4 waves x 16 rows.
__launch_bounds__(256,4)
__global__ void gemm_nt_pk2(const short* __restrict__ Ah, const short* __restrict__ Al,
                            const short* __restrict__ Bh, const short* __restrict__ Bl,
                            float* __restrict__ C, float scale)
{
  const int j = threadIdx.x;
  const int w = j>>6, lane = j&63;
  const int m_ = lane&15, qd = lane>>4;
  const long r0 = (long)blockIdx.x*64 + w*16;
  const long c0 = (long)blockIdx.y*64;
  f32x4 acc[4];
  #pragma unroll
  for (int nt=0;nt<4;++nt) acc[nt]=(f32x4){0.f,0.f,0.f,0.f};
  #pragma unroll
  for (int kt=0; kt<8; ++kt){
    int ko = kt*32 + (qd<<3);
    bf16x8 ah = *(const bf16x8*)(Ah + (r0+m_)*D_ + ko);
    bf16x8 al = *(const bf16x8*)(Al + (r0+m_)*D_ + ko);
    #pragma unroll
    for (int nt=0;nt<4;++nt){
      bf16x8 bh = *(const bf16x8*)(Bh + (c0+nt*16+m_)*D_ + ko);
      bf16x8 bl = *(const bf16x8*)(Bl + (c0+nt*16+m_)*D_ + ko);
      acc[nt]=mfma3(ah,al,bh,bl,acc[nt]);
    }
  }
  #pragma unroll
  for (int nt=0;nt<4;++nt){
    #pragma unroll
    for (int r=0;r<4;++r)
      C[(r0+qd*4+r)*S_ + c0 + nt*16 + m_] = acc[nt][r]*scale;
  }
}

// ---------------- top-k (register-resident) + sparse softmax-gather ----------------
__launch_bounds__(256,4)
__global__ void topk_gather(const float* __restrict__ sim, const float* __restrict__ xs,
                            const int* __restrict__ Kp, float* __restrict__ dynpre)
{
  __shared__ float wred[4]; __shared__ int ired[4];
  __shared__ float selw[256]; __shared__ int seli[256];
  __shared__ int cnt; __shared__ float sh_kth, sh_max, sh_den; __shared__ int sh_bi;
  const int s = blockIdx.x, j = threadIdx.x;
  const float* rp = sim + (long)s*S_;
  float vo[8], v[8];
  *(float4*)&vo[0] = *(const float4*)&rp[j*8];
  *(float4*)&vo[4] = *(const float4*)&rp[j*8+4];
  #pragma unroll
  for (int r=0;r<8;++r) v[r]=vo[r];
  if (j==0) cnt=0;
  const int K = Kp[0];
  for (int it=0; it<K; ++it){
    float m=-3.0e38f; int mi=0;
    #pragma unroll
    for (int r=0;r<8;++r){ if (v[r]>m){m=v[r]; mi=r;} }
    mi += j*8;
    #pragma unroll
    for (int o=32;o>=1;o>>=1){
      float om=__shfl_xor(m,o); int oi=__shfl_xor(mi,o);
      if (om>m){m=om;mi=oi;}
    }
    if ((j&63)==0){ wred[j>>6]=m; ired[j>>6]=mi; }
    __syncthreads();
    if (j==0){
      float bm=wred[0]; int bi=ired[0];
      #pragma unroll
      for (int w=1;w<4;++w) if (wred[w]>bm){bm=wred[w];bi=ired[w];}
      sh_kth=bm; sh_bi=bi;
      if (it==0) sh_max=bm;
    }
    __syncthreads();
    int sel = sh_bi - j*8;    // 0..7 iff this thread owns the winner
    #pragma unroll
    for (int r=0;r<8;++r) if (r==sel) v[r] = -3.0e38f;
  }
  const float kth=sh_kth, rmax=sh_max;
  #pragma unroll
  for (int r=0;r<8;++r){
    if (vo[r]>=kth){
      int p=atomicAdd(&cnt,1);
      if (p<256){ seli[p]=j*8+r; selw[p]=__expf(vo[r]-rmax); }
    }
  }
  __syncthreads();
  int c = cnt; if (c>256) c=256;
  {
    float p = (j<c)? selw[j] : 0.f;
    p = warp_sum64(p);
    if ((j&63)==0) wred[j>>6]=p;
    __syncthreads();
    if (j==0) sh_den = wred[0]+wred[1]+wred[2]+wred[3];
    __syncthreads();
  }
  float acc=0.f;
  for (int l=0;l<c;++l) acc += selw[l]*xs[(long)seli[l]*D_ + j];
  dynpre[(long)s*D_+j] = acc / sh_den;
}

// ---------------- hyper = sum_n ps[n] * reps[n] ----------------
__global__ void hyperwsum_kernel(const float* __restrict__ reps, const float* __restrict__ ps,
                                 float* __restrict__ hyper)
{
  long idx = (long)blockIdx.x*256+threadIdx.x;  // grid 2048
  hyper[idx] = ps[0]*reps[idx] + ps[1]*reps[(long)SD_+idx]
             + ps[2]*reps[2L*SD_+idx] + ps[3]*reps[3L*SD_+idx];
}

// ---------------- fusion ----------------
__global__ void fuse_kernel(const float* __restrict__ xs, const float* __restrict__ dyn,
                            const float* __restrict__ hyper, const float* __restrict__ beta,
                            float* __restrict__ fused)
{
  long idx = (long)blockIdx.x*256+threadIdx.x;  // grid 2048
  float b0=beta[0],b1=beta[1],b2=beta[2];
  float mx=fmaxf(b0,fmaxf(b1,b2));
  float e0=__expf(b0-mx),e1=__expf(b1-mx),e2=__expf(b2-mx);
  float inv=1.f/(e0+e1+e2);
  fused[idx] = e0*inv*xs[idx] + e1*inv*dyn[idx] + e2*inv*hyper[idx];
}

// ---------------- head ----------------
__global__ void head_kernel(const float* __restrict__ hh1, const float* __restrict__ Wm2,
                            const float* __restrict__ bm2, float* __restrict__ out)
{
  int r = blockIdx.x*32 + (threadIdx.x>>3);   // grid 64
  int sub = threadIdx.x&7;
  const float* hp = hh1 + (long)r*D_;
  float acc=0.f;
  for (int c=sub;c<D_;c+=8) acc += hp[c]*Wm2[c];
  acc += __shfl_xor(acc,1); acc += __shfl_xor(acc,2); acc += __shfl_xor(acc,4);
  if (sub==0) out[r]=acc+bm2[0];
}

// ---------------- launch ----------------
extern "C" void kernel_launch(void* const* d_in, const int* in_sizes, int n_in,
                              void* d_out, int out_size, void* d_ws, size_t ws_size,
                              hipStream_t stream)
{
  (void)in_sizes;(void)n_in;(void)out_size;(void)ws_size;
  const float* x        =(const float*)d_in[0];
  const float* snapshot =(const float*)d_in[1];
  const float* ps       =(const float*)d_in[2];
  const float* beta     =(const float*)d_in[3];
  const float* Wemb=(const float*)d_in[4];  const float* bemb=(const float*)d_in[5];
  const float* Wq  =(const float*)d_in[6];  const float* bq  =(const float*)d_in[7];
  const float* Wk  =(const float*)d_in[8];  const float* bk  =(const float*)d_in[9];
  const float* Wv  =(const float*)d_in[10]; const float* bv  =(const float*)d_in[11];
  const float* Wo  =(const float*)d_in[12]; const float* bo  =(const float*)d_in[13];
  const float* ln1g=(const float*)d_in[14]; const float* ln1b=(const float*)d_in[15];
  const float* Wint=(const float*)d_in[16]; const float* bint=(const float*)d_in[17];
  const float* Wmix=(const float*)d_in[18]; const float* bmix=(const float*)d_in[19];
  const float* ln2g=(const float*)d_in[20]; const float* ln2b=(const float*)d_in[21];
  const float* Wt  =(const float*)d_in[22]; const float* bt  =(const float*)d_in[23];
  const float* vt  =(const float*)d_in[24];
  const float* Wh1 =(const float*)d_in[25]; const float* bh1 =(const float*)d_in[26];
  const float* filt1=(const float*)d_in[27];
  const float* Wh2 =(const float*)d_in[28]; const float* bh2 =(const float*)d_in[29];
  const float* filt2=(const float*)d_in[30];
  const float* Wa  =(const float*)d_in[31]; const float* Wb  =(const float*)d_in[32];
  const float* Wg  =(const float*)d_in[33]; const float* bg  =(const float*)d_in[34];
  const float* Wm1 =(const float*)d_in[35]; const float* bm1 =(const float*)d_in[36];
  const float* Wm2 =(const float*)d_in[37]; const float* bm2 =(const float*)d_in[38];
  const int* numedges=(const int*)d_in[39];
  float* out=(float*)d_out;

  // ---- workspace layout (floats). Peak ~46.7 MB (unchanged). ----
  float* w = (float*)d_ws;
  // region [0 .. 4194304): overlays (stream-ordered): pe -> repsb -> sim
  float* pe    = w;
  float* repsb = w;
  float* sim   = w;
  float* P     = w + 4194304;            // NS*E*D = 131072
  float* Dv    = P + 131072;             // 8192
  float* De    = Dv + 8192;              // 512
  int*   ecnt  = (int*)(De + 512);       // 512
  int*   scnt  = ecnt + 512;             // 8192
  int*   ei    = scnt + 8192;            // 131072 (NS*E*256) @4342784
  float* ev    = (float*)(ei + 131072);  // 131072
  int*   si    = (int*)(ev + 131072);    // 262144 (NS*S*32)
  float* sv    = (float*)(si + 262144);  // 262144  -> ends at 5129216
  // packed p1 planes overlay ei/ev (dead after last applyA): 2 x 524288 shorts
  short* p1h   = (short*)(w + 4342784);
  short* p1l   = p1h + 524288;           // ends at float 4867072 (= si start; si also dead)
  short* pk2   = (short*)(w + PK2BASE);  // 6 tail-GEMM weights, ends at 5636096
  short* q1h   = (short*)(w + 5636096);  // 2 x 524288 shorts -> ends 6160384 < 6431232
  short* q1l   = q1h + 524288;
  float* xs    = w + 6431232;
  float* hyper = xs + SD_;
  float* bufA  = hyper + SD_;            // NS*SD
  float* bufB  = bufA + 4*SD_;           // NS*SD
  float* dynpre= bufA + 2*SD_;
  float* dyn   = bufA + 3*SD_;
  float* fused = bufB;
  float* hh1   = bufB + SD_;
  short* pkc   = (short*)(w + PKBASE);   // 2MB combined packed weights

  hipMemsetAsync(De, 0, (size_t)NS_*E_*sizeof(float), stream);
  pe_kernel<<<64,256,0,stream>>>(pe);
  pack_all<<<dim3(256,14),256,0,stream>>>(Wq,Wk,Wv,Wo,Wint,Wt,Wmix,
                                          Wh1,Wh2,Wa,Wb,Wg,Wm1,pkc,pk2);

  stageA_kernel<<<S_,512,0,stream>>>(x,pe,Wemb,bemb,bq,bk,bv,bo,
                                     ln1g,ln1b,bint,bmix,ln2g,ln2b,bt,vt,
                                     pkc,xs);
  hg_deg<<<dim3(32,NS_),256,0,stream>>>(snapshot,Dv,De);
  build_ecsr<<<dim3(E_,NS_),256,0,stream>>>(snapshot,Dv,ei,ev,ecnt);
  build_scsr<<<dim3(8,NS_),256,0,stream>>>(snapshot,Dv,De,si,sv,scnt);

  auto applyA=[&](const float* M, long mz,
                  const float* X1, long x1z, float c1,
                  const float* X2, long x2z, float c2, float c3,
                  const float* filt, int uf, float* outb){
    hg_p1<<<dim3(E_,NS_),256,0,stream>>>(ei,ev,ecnt,M,mz,P);
    hg_p2<<<dim3(S_/8,NS_),256,0,stream>>>(si,sv,scnt,P,X1,x1z,c1,X2,x2z,c2,c3,filt,uf,outb);
  };

  // ---- wavelet hypergraph conv, layer 1 ----
  applyA(xs,0,     xs,0,1.f,    nullptr,0,0.f,  -1.f,  nullptr,0, bufA);  // t1 = L z
  applyA(bufA,SD_, xs,0,1.f,    bufA,SD_,1.5f,  -0.5f, filt1,1,   bufB);  // y0
  applyA(bufB,SD_, bufB,SD_,1.f, nullptr,0,0.f, -1.f,  nullptr,0, bufA);  // t3
  applyA(bufA,SD_, bufB,SD_,1.f, bufA,SD_,-0.5f,-0.5f, nullptr,0, bufA);  // p
  gemm_pk<<<dim3(128,4),256,0,stream>>>(bufA, pk2+PKH1, bufB, nullptr,nullptr, bh1, 2);

  // ---- layer 2 ----
  applyA(bufB,SD_, bufB,SD_,1.f, nullptr,0,0.f, -1.f,  nullptr,0, bufA);
  applyA(bufA,SD_, bufB,SD_,1.f, bufA,SD_,1.5f, -0.5f, filt2,1,   bufB);
  applyA(bufB,SD_, bufB,SD_,1.f, nullptr,0,0.f, -1.f,  nullptr,0, bufA);
  applyA(bufA,SD_, bufB,SD_,1.f, bufA,SD_,-0.5f,-0.5f, nullptr,0, bufA);
  gemm_pk<<<dim3(128,4),256,0,stream>>>(bufA, pk2+PKH2, repsb, nullptr,nullptr, bh2, 0);
  hyperwsum_kernel<<<2048,256,0,stream>>>(repsb,ps,hyper);

  // ---- dynamic graph (p1/q1 emitted directly as packed bf16 planes) ----
  gemm_pk<<<dim3(32,4),256,0,stream>>>(xs, pk2+PKA, nullptr, p1h, p1l, nullptr, 0);
  gemm_pk<<<dim3(32,4),256,0,stream>>>(xs, pk2+PKB, nullptr, q1h, q1l, nullptr, 0);
  gemm_nt_pk2<<<dim3(32,32),256,0,stream>>>(p1h,p1l,q1h,q1l,sim,0.0625f);
  topk_gather<<<S_,256,0,stream>>>(sim,xs,numedges,dynpre);
  gemm_pk<<<dim3(32,4),256,0,stream>>>(dynpre, pk2+PKG, dyn, nullptr,nullptr, bg, 1);

  // ---- fusion + head ----
  fuse_kernel<<<2048,256,0,stream>>>(xs,dyn,hyper,beta,fused);
  gemm_pk<<<dim3(32,4),256,0,stream>>>(fused, pk2+PKM1, hh1, nullptr,nullptr, bm1, 1);
  head_kernel<<<64,256,0,stream>>>(hh1,Wm2,bm2,out);
}